// Round 9
// baseline (446.883 us; speedup 1.0000x reference)
//
#include <hip/hip_runtime.h>

// DesignerNetwork: B=1024 batch-independent graph-GRU network.
// Round 9: identical to round 8 (packed d_ws, chunked successor batching,
// split finalize, opaque-pinned weight regs) with __launch_bounds__(256,4):
// VGPR demand is 88 < 128 cap, LDS 37.9KB*4 fits 160KB -> 4 blocks/CU
// (16 waves/CU) instead of 2, doubling latency-hiding. Grid 1024 = 256CU*4
// -> exactly fully resident, no tail.

namespace {

typedef float v2f __attribute__((ext_vector_type(2)));

constexpr int Bc = 1024;   // batch
constexpr int Nn = 32;     // nodes
constexpr int SP = 60;     // S_PHI == S_RHO
constexpr int NA = 5;      // actions
constexpr int NR = 7;      // roles

// ---- d_ws float layout (packed weights) ----
// WHH: [dir2][gate3][lane64][wave4][16f]  = 24576 floats @ 0
// WIH: same                               = 24576 floats @ 24576
// WP : [dir2][lane64][wave4][20f]         = 10240 floats @ 49152
constexpr int WS_WIH = 24576;
constexpr int WS_WP  = 49152;
constexpr int WS_TOTAL = 59392;
constexpr int DSTRIDE_G = 12288;   // per-dir stride for WHH/WIH regions
constexpr int DSTRIDE_P = 5120;    // per-dir stride for WP region

// ---- LDS layout (float offsets) ----
constexpr int OFF_ST   = 0;                    // states [32][64]
constexpr int OFF_RP   = OFF_ST + Nn * 64;     // rho partials [2][4][64]
constexpr int OFF_PART = OFF_RP + 512;         // chunk partials [4][4][64][4]
constexpr int OFF_ZDZ  = OFF_PART + 4096;      // z/dz staged [32][20]
constexpr int OFF_PSI  = OFF_ZDZ + Nn * 20;    // psi raw [32][8]
constexpr int OFF_WU   = OFF_PSI + Nn * 8;     // Wu 7x120
constexpr int OFF_WA   = OFF_WU + 840;         // Wa 5x120
constexpr int OFF_WC   = OFF_WA + 600;         // Wc 120
constexpr int OFF_BA   = OFF_WC + 120;         // ba (pad 8)
constexpr int OFF_BU   = OFF_BA + 8;           // bu (pad 8)
constexpr int OFF_BC   = OFF_BU + 8;           // bc (pad 4)
constexpr int OFF_HAS  = OFF_BC + 4;           // has[32]
constexpr int OFF_AF   = OFF_HAS + 32;         // alpha_f [64]
constexpr int OFF_AB   = OFF_AF + 64;          // alpha_b [64]
constexpr int OFF_OS   = OFF_AB + 64;          // omega scratch [8]
constexpr int OFF_MASK = OFF_OS + 8;           // uints: succ[32] pred[32] flags[4]
constexpr int LDS_FLOATS = OFF_MASK + 68 + 8;  // 9376 floats = 37.5KB

__device__ __forceinline__ float sigm(float x) {
    return 1.0f / (1.0f + __expf(-x));
}

__device__ __forceinline__ float tanh_f(float x) {
    float e = __expf(fminf(2.0f * x, 80.0f));
    return (e - 1.0f) / (e + 1.0f);
}

// adj may arrive as int32 (0/1), packed uint8 bool, or float32. mode: 0/1/2.
__device__ __forceinline__ unsigned adj_nz(const unsigned* a, int mode, int r, int c) {
    const int idx = r * 32 + c;
    unsigned v = (mode == 1) ? ((a[idx >> 2] >> (8 * (idx & 3))) & 0xffu) : a[idx];
    return v != 0u ? 1u : 0u;
}

// 3-gate dot of the register-resident weight slice with 8-v2f x slice.
__device__ __forceinline__ void matvec3(const v2f (&W)[3][8], const v2f* x,
                                        float& r0, float& r1, float& r2) {
    v2f a0 = {0.f, 0.f}, a1 = {0.f, 0.f}, a2 = {0.f, 0.f};
#pragma unroll
    for (int p = 0; p < 8; ++p) {
        const v2f xp = x[p];
        a0 = __builtin_elementwise_fma(W[0][p], xp, a0);
        a1 = __builtin_elementwise_fma(W[1][p], xp, a1);
        a2 = __builtin_elementwise_fma(W[2][p], xp, a2);
    }
    r0 = a0.x + a0.y; r1 = a1.x + a1.y; r2 = a2.x + a2.y;
}

// Load this thread's weight slices into registers, pinned via opaque *1.0f
// (product depends on a register -> not rematerializable, not foldable).
__device__ __forceinline__ void load_w(const float* __restrict__ ws, int d,
        int w, int lane, v2f onev,
        v2f (&wh)[3][8], v2f (&wx)[3][8], v2f (&wp)[10]) {
    const v2f* WH = (const v2f*)(ws + d * DSTRIDE_G + ((lane * 4 + w) << 4));
    const v2f* WX = (const v2f*)(ws + WS_WIH + d * DSTRIDE_G + ((lane * 4 + w) << 4));
    const v2f* WPp = (const v2f*)(ws + WS_WP + d * DSTRIDE_P + (lane * 4 + w) * 20);
#pragma unroll
    for (int g = 0; g < 3; ++g)
#pragma unroll
        for (int p = 0; p < 8; ++p) {
            wh[g][p] = WH[g * 2048 + p] * onev;
            wx[g][p] = WX[g * 2048 + p] * onev;
        }
#pragma unroll
    for (int p = 0; p < 10; ++p) wp[p] = WPp[p] * onev;
}

// ---- weight pre-pack kernel (runs before dn_kernel on the same stream) ----
__global__ void pack_kernel(const float* __restrict__ Whh_f, const float* __restrict__ Wih_f,
                            const float* __restrict__ Wf,
                            const float* __restrict__ Whh_b, const float* __restrict__ Wih_b,
                            const float* __restrict__ Wb, float* __restrict__ ws) {
    const int idx = blockIdx.x * 256 + threadIdx.x;
    if (idx < 2 * 24576) {
        const int which = idx / 24576;      // 0=WHH, 1=WIH
        int r = idx % 24576;
        const int j = r & 15; r >>= 4;
        const int w = r & 3;  r >>= 2;
        const int lane = r & 63; r >>= 6;
        const int g = r % 3;
        const int d = r / 3;
        const int k = 16 * w + j;
        const float* src = which ? (d ? Wih_b : Wih_f) : (d ? Whh_b : Whh_f);
        ws[idx] = (lane < 60 && k < 60) ? src[(g * 60 + lane) * 60 + k] : 0.f;
    } else if (idx < WS_TOTAL) {
        int r = idx - WS_WP;
        const int jj = r % 20; r /= 20;
        const int w = r & 3;  r >>= 2;
        const int lane = r & 63;
        const int d = r >> 6;
        const float* src = d ? Wb : Wf;
        const int pk = (w < 3) ? 20 * w : 60;
        ws[idx] = (lane < 60) ? src[lane * 80 + pk + jj] : 0.f;
    }
}

template <int FWD>
__device__ __forceinline__ void run_dir(float* lds,
        const v2f (&wh)[3][8], const v2f (&wx)[3][8], const v2f (&wp)[10],
        const float* __restrict__ bih, const float* __restrict__ bhh,
        const float* __restrict__ bp, int w, int lane, int ln, int& par) {
    float* st = lds + OFF_ST;
    const unsigned* succm = (const unsigned*)(lds + OFF_MASK);
    const unsigned* predm = succm + 32;

    const float b0s = bih[ln] + bhh[ln];
    const float b1s = bih[60 + ln] + bhh[60 + ln];
    const float b2i = bih[120 + ln];
    const float b2h = bhh[120 + ln];
    const float bpv = bp[ln];

    for (int s = 0; s < Nn; ++s) {
        const int t = FWD ? s : (Nn - 1 - s);

        // ---- finalize rho[t]: cooperative proj over [h(60); z(10); dz(10)] ----
        v2f pa = {0.f, 0.f};
        const v2f* xb = (w < 3) ? ((const v2f*)(st + t * 64) + 10 * w)
                                : ((const v2f*)(lds + OFF_ZDZ + t * 20));
#pragma unroll
        for (int p = 0; p < 10; ++p)
            pa = __builtin_elementwise_fma(wp[p], xb[p], pa);
        lds[OFF_RP + (par * 4 + w) * 64 + lane] = pa.x + pa.y;
        __syncthreads();
        float sum = lds[OFF_RP + (par * 4 + 0) * 64 + lane]
                  + lds[OFF_RP + (par * 4 + 1) * 64 + lane]
                  + lds[OFF_RP + (par * 4 + 2) * 64 + lane]
                  + lds[OFF_RP + (par * 4 + 3) * 64 + lane] + bpv;
        par ^= 1;
        const float rho = FWD ? tanh_f(sum) : sum;
        if (lane < SP) st[t * 64 + lane] = rho;   // replicated identical write
        // (own-wave LDS write->read below is in-order; no barrier needed)

        // ---- GRU pushes, gated by has[t]; successors batched 4 per round ----
        const float hb = lds[OFF_HAS + t];
        unsigned m = (hb != 0.f) ? (FWD ? succm[t] : predm[t]) : 0u;
        if (m) {
            float gi0, gi1, gi2;      // x-side slice of rho[t], hoisted per node
            matvec3(wx, (const v2f*)(st + t * 64) + 8 * w, gi0, gi1, gi2);
            while (m) {
                int i0 = __ffs(m) - 1; m &= m - 1u;
                int i1 = -1, i2 = -1, i3 = -1, cnt = 1;
                if (m) { i1 = __ffs(m) - 1; m &= m - 1u; ++cnt;
                    if (m) { i2 = __ffs(m) - 1; m &= m - 1u; ++cnt;
                        if (m) { i3 = __ffs(m) - 1; m &= m - 1u; ++cnt; } } }
                {
                    float g0, g1, g2;
                    matvec3(wh, (const v2f*)(st + i0 * 64) + 8 * w, g0, g1, g2);
                    float4 q = {gi0 + g0, gi1 + g1, gi2, g2};
                    *(float4*)(lds + OFF_PART + ((0 * 4 + w) * 64 + lane) * 4) = q;
                }
                if (cnt > 1) {
                    float g0, g1, g2;
                    matvec3(wh, (const v2f*)(st + i1 * 64) + 8 * w, g0, g1, g2);
                    float4 q = {gi0 + g0, gi1 + g1, gi2, g2};
                    *(float4*)(lds + OFF_PART + ((1 * 4 + w) * 64 + lane) * 4) = q;
                }
                if (cnt > 2) {
                    float g0, g1, g2;
                    matvec3(wh, (const v2f*)(st + i2 * 64) + 8 * w, g0, g1, g2);
                    float4 q = {gi0 + g0, gi1 + g1, gi2, g2};
                    *(float4*)(lds + OFF_PART + ((2 * 4 + w) * 64 + lane) * 4) = q;
                }
                if (cnt > 3) {
                    float g0, g1, g2;
                    matvec3(wh, (const v2f*)(st + i3 * 64) + 8 * w, g0, g1, g2);
                    float4 q = {gi0 + g0, gi1 + g1, gi2, g2};
                    *(float4*)(lds + OFF_PART + ((3 * 4 + w) * 64 + lane) * 4) = q;
                }
                __syncthreads();
                if (w < cnt) {        // wave w finalizes successor #w of chunk
                    const int it = (w == 0) ? i0 : (w == 1) ? i1 : (w == 2) ? i2 : i3;
                    const float4 q0 = *(const float4*)(lds + OFF_PART + ((w * 4 + 0) * 64 + lane) * 4);
                    const float4 q1 = *(const float4*)(lds + OFF_PART + ((w * 4 + 1) * 64 + lane) * 4);
                    const float4 q2 = *(const float4*)(lds + OFF_PART + ((w * 4 + 2) * 64 + lane) * 4);
                    const float4 q3 = *(const float4*)(lds + OFF_PART + ((w * 4 + 3) * 64 + lane) * 4);
                    const float a0  = q0.x + q1.x + q2.x + q3.x + b0s;
                    const float a1  = q0.y + q1.y + q2.y + q3.y + b1s;
                    const float a2i = q0.z + q1.z + q2.z + q3.z + b2i;
                    const float a2h = q0.w + q1.w + q2.w + q3.w + b2h;
                    const float r = sigm(a0);
                    const float u = sigm(a1);
                    const float n = tanh_f(fmaf(r, a2h, a2i));
                    const float hold = st[it * 64 + lane];   // pre-update h
                    const float hnew = fmaf(u, hold - n, n);
                    if (lane < SP) st[it * 64 + lane] = hnew;
                }
                __syncthreads();
            }
        }
    }

    // ---- alpha scan (single GRU chain; wave 0 finalizes) ----
    float* ah = lds + (FWD ? OFF_AF : OFF_AB);
    ah[lane] = 0.f;                               // replicated identical write
    const int acn = FWD ? 5 : 6;
    for (int s2 = 0; s2 < acn; ++s2) {
        const int i = FWD ? (Nn - 5 + s2) : (5 - s2);
        if (lds[OFF_HAS + i] == 0.f) continue;    // block-uniform skip
        float gi0, gi1, gi2, g0, g1, g2;
        matvec3(wx, (const v2f*)(st + i * 64) + 8 * w, gi0, gi1, gi2);
        matvec3(wh, (const v2f*)(ah) + 8 * w, g0, g1, g2);
        float4 q = {gi0 + g0, gi1 + g1, gi2, g2};
        *(float4*)(lds + OFF_PART + (w * 64 + lane) * 4) = q;
        __syncthreads();
        if (w == 0) {
            const float4 q0 = *(const float4*)(lds + OFF_PART + ((0 * 64) + lane) * 4);
            const float4 q1 = *(const float4*)(lds + OFF_PART + ((1 * 64) + lane) * 4);
            const float4 q2 = *(const float4*)(lds + OFF_PART + ((2 * 64) + lane) * 4);
            const float4 q3 = *(const float4*)(lds + OFF_PART + ((3 * 64) + lane) * 4);
            const float a0  = q0.x + q1.x + q2.x + q3.x + b0s;
            const float a1  = q0.y + q1.y + q2.y + q3.y + b1s;
            const float a2i = q0.z + q1.z + q2.z + q3.z + b2i;
            const float a2h = q0.w + q1.w + q2.w + q3.w + b2h;
            const float r = sigm(a0);
            const float u = sigm(a1);
            const float n = tanh_f(fmaf(r, a2h, a2i));
            const float hold = ah[lane];
            const float hnew = fmaf(u, hold - n, n);
            if (lane < SP) ah[lane] = hnew;
        }
        __syncthreads();
    }
}

__device__ void run_heads(float* lds, int b, int lane, float* __restrict__ out) {
    const float* aF = lds + OFF_AF;
    const float* aB = lds + OFF_AB;

    float o = 0.f;
    if (lane < NA) {
        o = lds[OFF_BA + lane];
        const float* wa = lds + OFF_WA + lane * 120;
#pragma unroll
        for (int k = 0; k < SP; ++k) o = fmaf(wa[k], aF[k], o);
#pragma unroll
        for (int k = 0; k < SP; ++k) o = fmaf(wa[60 + k], aB[k], o);
        lds[OFF_OS + lane] = o;
    } else if (lane == NA) {
        float v = lds[OFF_BC];
        const float* wc = lds + OFF_WC;
#pragma unroll
        for (int k = 0; k < SP; ++k) v = fmaf(wc[k], aF[k], v);
#pragma unroll
        for (int k = 0; k < SP; ++k) v = fmaf(wc[60 + k], aB[k], v);
        out[Bc * NA + Bc * NR * Nn + b] = v;
    }
    __builtin_amdgcn_wave_barrier();

    if (lane < NA) {
        const float* os = lds + OFF_OS;
        float mx = os[0];
#pragma unroll
        for (int j = 1; j < NA; ++j) mx = fmaxf(mx, os[j]);
        float sum = 0.f;
#pragma unroll
        for (int j = 0; j < NA; ++j) sum += __expf(os[j] - mx);
        out[b * NA + lane] = __expf(o - mx) / sum;
    }

    if (lane < Nn) {
        const int i = lane;
        const float mk = lds[OFF_HAS + i];
        float p[NR];
        float mx = -1e30f;
#pragma unroll
        for (int c = 0; c < NR; ++c) {
            const float v = (mk != 0.f)
                ? (lds[OFF_PSI + i * 8 + c] + lds[OFF_BU + c])
                : -60.0f;
            p[c] = v;
            mx = fmaxf(mx, v);
        }
        float sum = 0.f;
#pragma unroll
        for (int c = 0; c < NR; ++c) { p[c] = __expf(p[c] - mx); sum += p[c]; }
        const float inv = 1.0f / sum;
#pragma unroll
        for (int c = 0; c < NR; ++c)
            out[Bc * NA + b * (NR * Nn) + c * Nn + i] = p[c] * inv;
    }
}

__global__ __launch_bounds__(256, 4)
void dn_kernel(const float* __restrict__ has, const float* __restrict__ z,
               const float* __restrict__ dz, const unsigned* __restrict__ adjw,
               const float* __restrict__ bih_f, const float* __restrict__ bhh_f,
               const float* __restrict__ bih_b, const float* __restrict__ bhh_b,
               const float* __restrict__ bf, const float* __restrict__ bb,
               const float* __restrict__ Wa, const float* __restrict__ ba,
               const float* __restrict__ Wc, const float* __restrict__ bc,
               const float* __restrict__ Wu, const float* __restrict__ bu,
               const float* __restrict__ ws, float* __restrict__ out) {
    __shared__ float lds[LDS_FLOATS];
    const int tid = threadIdx.x;
    const int lane = tid & 63;
    const int w = tid >> 6;
    const int b = blockIdx.x;
    const int ln = (lane < SP) ? lane : (SP - 1);   // clamp for bias loads

    unsigned* succm = (unsigned*)(lds + OFF_MASK);
    unsigned* predm = succm + 32;
    unsigned* flags = predm + 32;

    if (tid < 4) flags[tid] = 0u;
    __syncthreads();

    // ---- adj dtype detection (first 256 words only) ----
    {
        unsigned ff = 0u, fb = 0u;
        for (int i = tid; i < 256; i += 256) {
            const unsigned v = adjw[i];
            ff |= (v == 0x3f800000u) ? 1u : 0u;
            fb |= (v > 1u && v != 0x3f800000u) ? 1u : 0u;
        }
        if (ff) atomicOr(&flags[0], 1u);
        if (fb) atomicOr(&flags[1], 1u);
    }

    // ---- stage head weights, has, z/dz; zero state array ----
    for (int i = tid; i < 840; i += 256) lds[OFF_WU + i] = Wu[i];
    for (int i = tid; i < 600; i += 256) lds[OFF_WA + i] = Wa[i];
    if (tid < 120) lds[OFF_WC + tid] = Wc[tid];
    if (tid < NR) lds[OFF_BU + tid] = bu[tid];
    if (tid < NA) lds[OFF_BA + tid] = ba[tid];
    if (tid == 0) lds[OFF_BC] = bc[0];
    if (tid < Nn) lds[OFF_HAS + tid] = has[b * 32 + tid];
    for (int i = tid; i < Nn * 20; i += 256) {
        const int t = i / 20, k = i - t * 20;
        lds[OFF_ZDZ + i] = (k < 10) ? z[(b * Nn + t) * 10 + k]
                                    : dz[(b * Nn + t) * 10 + (k - 10)];
    }
    for (int i = tid; i < Nn * 64; i += 256) lds[OFF_ST + i] = 0.f;
    __syncthreads();

    // ---- adjacency bitmasks ----
    const int mode = flags[0] ? 2 : (flags[1] ? 1 : 0);
    if (tid < 32) {
        unsigned sm = 0u;
        for (int c = 0; c < 32; ++c) sm |= adj_nz(adjw, mode, tid, c) << c;
        succm[tid] = sm;
    } else if (tid < 64) {
        const int c = tid - 32;
        unsigned pm = 0u;
        for (int r = 0; r < 32; ++r) pm |= adj_nz(adjw, mode, r, c) << r;
        predm[c] = pm;
    }
    __syncthreads();

    // ---- opaque 1.0f: pins weight registers against rematerialization ----
    float one = 1.0f;
    asm volatile("" : "+v"(one));
    const v2f onev = {one, one};

    int par = 0;
    v2f wh[3][8], wx[3][8], wp[10];

    // ---- forward direction ----
    load_w(ws, 0, w, lane, onev, wh, wx, wp);
    run_dir<1>(lds, wh, wx, wp, bih_f, bhh_f, bf, w, lane, ln, par);
    __syncthreads();

    // ---- psi pass 1 (fwd half) while rho_f still in ST ----
    if (tid < Nn * NR) {
        const int i = tid / NR, c = tid - i * NR;
        const float* wu = lds + OFF_WU + c * 120;
        const float* sf = lds + OFF_ST + i * 64;
        float acc = 0.f;
#pragma unroll
        for (int k = 0; k < SP; ++k) acc = fmaf(wu[k], sf[k], acc);
        lds[OFF_PSI + i * 8 + c] = acc;
    }
    __syncthreads();

    // ---- re-zero ST for backward direction ----
    for (int i = tid; i < Nn * 64; i += 256) lds[OFF_ST + i] = 0.f;
    __syncthreads();

    // ---- backward direction ----
    load_w(ws, 1, w, lane, onev, wh, wx, wp);
    run_dir<0>(lds, wh, wx, wp, bih_b, bhh_b, bb, w, lane, ln, par);
    __syncthreads();

    // ---- psi pass 2 (bwd half) ----
    if (tid < Nn * NR) {
        const int i = tid / NR, c = tid - i * NR;
        const float* wu = lds + OFF_WU + c * 120 + 60;
        const float* sb = lds + OFF_ST + i * 64;
        float acc = 0.f;
#pragma unroll
        for (int k = 0; k < SP; ++k) acc = fmaf(wu[k], sb[k], acc);
        lds[OFF_PSI + i * 8 + c] += acc;
    }
    __syncthreads();

    if (w == 0) run_heads(lds, b, lane, out);
}

}  // namespace

extern "C" void kernel_launch(void* const* d_in, const int* in_sizes, int n_in,
                              void* d_out, int out_size, void* d_ws, size_t ws_size,
                              hipStream_t stream) {
    (void)in_sizes; (void)n_in; (void)out_size; (void)ws_size;
    const float* has     = (const float*)d_in[0];
    const float* z       = (const float*)d_in[1];
    const float* dz      = (const float*)d_in[2];
    const unsigned* adjw = (const unsigned*)d_in[3];
    const float* Wih_f   = (const float*)d_in[4];
    const float* Whh_f   = (const float*)d_in[5];
    const float* bih_f   = (const float*)d_in[6];
    const float* bhh_f   = (const float*)d_in[7];
    const float* Wih_b   = (const float*)d_in[8];
    const float* Whh_b   = (const float*)d_in[9];
    const float* bih_b   = (const float*)d_in[10];
    const float* bhh_b   = (const float*)d_in[11];
    const float* Wf      = (const float*)d_in[12];
    const float* bf      = (const float*)d_in[13];
    const float* Wb      = (const float*)d_in[14];
    const float* bb      = (const float*)d_in[15];
    const float* Wa      = (const float*)d_in[16];
    const float* ba      = (const float*)d_in[17];
    const float* Wc      = (const float*)d_in[18];
    const float* bc      = (const float*)d_in[19];
    const float* Wu      = (const float*)d_in[20];
    const float* bu      = (const float*)d_in[21];
    float* out = (float*)d_out;
    float* ws  = (float*)d_ws;   // needs WS_TOTAL*4 = 237.6KB of scratch

    pack_kernel<<<(WS_TOTAL + 255) / 256, 256, 0, stream>>>(
        Whh_f, Wih_f, Wf, Whh_b, Wih_b, Wb, ws);

    dn_kernel<<<Bc, 256, 0, stream>>>(
        has, z, dz, adjw,
        bih_f, bhh_f, bih_b, bhh_b, bf, bb,
        Wa, ba, Wc, bc, Wu, bu, ws, out);
}

// Round 10
// 371.876 us; speedup vs baseline: 1.2017x; 1.2017x over previous
//
#include <hip/hip_runtime.h>

// DesignerNetwork: B=1024 batch-independent graph-GRU network.
// Round 10: round-8 structure and (256,2) launch bounds (the proven-safe
// config, 295us), plus TRUE register pinning of the per-edge hot weight
// matrix wh via per-value `asm volatile` identity (volatile asm results
// cannot be rematerialized -> 48 VGPRs stay live). Diagnosis: round 8 was
// L1-BW-bound re-streaming weight slices every matvec (~200KB/chunk-round,
// ~2700cyc/round); wh covers the dominant per-edge rounds. wx/wp (per-node)
// still stream. min_waves>=4 is poison (r4/r9: allocator targets 64 regs
// and spills) -- stay at (256,2).

namespace {

typedef float v2f __attribute__((ext_vector_type(2)));

constexpr int Bc = 1024;   // batch
constexpr int Nn = 32;     // nodes
constexpr int SP = 60;     // S_PHI == S_RHO
constexpr int NA = 5;      // actions
constexpr int NR = 7;      // roles

// ---- d_ws float layout (packed weights) ----
// WHH: [dir2][gate3][lane64][wave4][16f]  = 24576 floats @ 0
// WIH: same                               = 24576 floats @ 24576
// WP : [dir2][lane64][wave4][20f]         = 10240 floats @ 49152
constexpr int WS_WIH = 24576;
constexpr int WS_WP  = 49152;
constexpr int WS_TOTAL = 59392;
constexpr int DSTRIDE_G = 12288;   // per-dir stride for WHH/WIH regions
constexpr int DSTRIDE_P = 5120;    // per-dir stride for WP region

// ---- LDS layout (float offsets) ----
constexpr int OFF_ST   = 0;                    // states [32][64]
constexpr int OFF_RP   = OFF_ST + Nn * 64;     // rho partials [2][4][64]
constexpr int OFF_PART = OFF_RP + 512;         // chunk partials [4][4][64][4]
constexpr int OFF_ZDZ  = OFF_PART + 4096;      // z/dz staged [32][20]
constexpr int OFF_PSI  = OFF_ZDZ + Nn * 20;    // psi raw [32][8]
constexpr int OFF_WU   = OFF_PSI + Nn * 8;     // Wu 7x120
constexpr int OFF_WA   = OFF_WU + 840;         // Wa 5x120
constexpr int OFF_WC   = OFF_WA + 600;         // Wc 120
constexpr int OFF_BA   = OFF_WC + 120;         // ba (pad 8)
constexpr int OFF_BU   = OFF_BA + 8;           // bu (pad 8)
constexpr int OFF_BC   = OFF_BU + 8;           // bc (pad 4)
constexpr int OFF_HAS  = OFF_BC + 4;           // has[32]
constexpr int OFF_AF   = OFF_HAS + 32;         // alpha_f [64]
constexpr int OFF_AB   = OFF_AF + 64;          // alpha_b [64]
constexpr int OFF_OS   = OFF_AB + 64;          // omega scratch [8]
constexpr int OFF_MASK = OFF_OS + 8;           // uints: succ[32] pred[32] flags[4]
constexpr int LDS_FLOATS = OFF_MASK + 68 + 8;  // 9376 floats = 37.5KB

__device__ __forceinline__ float sigm(float x) {
    return 1.0f / (1.0f + __expf(-x));
}

__device__ __forceinline__ float tanh_f(float x) {
    float e = __expf(fminf(2.0f * x, 80.0f));
    return (e - 1.0f) / (e + 1.0f);
}

// Volatile-asm identity: result is "produced by unknown asm" -> the value
// CANNOT be rematerialized by re-loading; it must stay in a register.
__device__ __forceinline__ v2f pin(v2f x) {
    asm volatile("" : "+v"(x));
    return x;
}

// adj may arrive as int32 (0/1), packed uint8 bool, or float32. mode: 0/1/2.
__device__ __forceinline__ unsigned adj_nz(const unsigned* a, int mode, int r, int c) {
    const int idx = r * 32 + c;
    unsigned v = (mode == 1) ? ((a[idx >> 2] >> (8 * (idx & 3))) & 0xffu) : a[idx];
    return v != 0u ? 1u : 0u;
}

// 3-gate dot of the register-resident weight slice with 8-v2f x slice.
__device__ __forceinline__ void matvec3(const v2f (&W)[3][8], const v2f* x,
                                        float& r0, float& r1, float& r2) {
    v2f a0 = {0.f, 0.f}, a1 = {0.f, 0.f}, a2 = {0.f, 0.f};
#pragma unroll
    for (int p = 0; p < 8; ++p) {
        const v2f xp = x[p];
        a0 = __builtin_elementwise_fma(W[0][p], xp, a0);
        a1 = __builtin_elementwise_fma(W[1][p], xp, a1);
        a2 = __builtin_elementwise_fma(W[2][p], xp, a2);
    }
    r0 = a0.x + a0.y; r1 = a1.x + a1.y; r2 = a2.x + a2.y;
}

// Load this thread's weight slices. wh (per-edge hot) is HARD-pinned in
// VGPRs via volatile asm; wx/wp (per-node) may stream from L1.
__device__ __forceinline__ void load_w(const float* __restrict__ ws, int d,
        int w, int lane, v2f onev,
        v2f (&wh)[3][8], v2f (&wx)[3][8], v2f (&wp)[10]) {
    const v2f* WH = (const v2f*)(ws + d * DSTRIDE_G + ((lane * 4 + w) << 4));
    const v2f* WX = (const v2f*)(ws + WS_WIH + d * DSTRIDE_G + ((lane * 4 + w) << 4));
    const v2f* WPp = (const v2f*)(ws + WS_WP + d * DSTRIDE_P + (lane * 4 + w) * 20);
#pragma unroll
    for (int g = 0; g < 3; ++g)
#pragma unroll
        for (int p = 0; p < 8; ++p) {
            wh[g][p] = pin(WH[g * 2048 + p]);
            wx[g][p] = WX[g * 2048 + p] * onev;
        }
#pragma unroll
    for (int p = 0; p < 10; ++p) wp[p] = WPp[p] * onev;
}

// ---- weight pre-pack kernel (runs before dn_kernel on the same stream) ----
__global__ void pack_kernel(const float* __restrict__ Whh_f, const float* __restrict__ Wih_f,
                            const float* __restrict__ Wf,
                            const float* __restrict__ Whh_b, const float* __restrict__ Wih_b,
                            const float* __restrict__ Wb, float* __restrict__ ws) {
    const int idx = blockIdx.x * 256 + threadIdx.x;
    if (idx < 2 * 24576) {
        const int which = idx / 24576;      // 0=WHH, 1=WIH
        int r = idx % 24576;
        const int j = r & 15; r >>= 4;
        const int w = r & 3;  r >>= 2;
        const int lane = r & 63; r >>= 6;
        const int g = r % 3;
        const int d = r / 3;
        const int k = 16 * w + j;
        const float* src = which ? (d ? Wih_b : Wih_f) : (d ? Whh_b : Whh_f);
        ws[idx] = (lane < 60 && k < 60) ? src[(g * 60 + lane) * 60 + k] : 0.f;
    } else if (idx < WS_TOTAL) {
        int r = idx - WS_WP;
        const int jj = r % 20; r /= 20;
        const int w = r & 3;  r >>= 2;
        const int lane = r & 63;
        const int d = r >> 6;
        const float* src = d ? Wb : Wf;
        const int pk = (w < 3) ? 20 * w : 60;
        ws[idx] = (lane < 60) ? src[lane * 80 + pk + jj] : 0.f;
    }
}

template <int FWD>
__device__ __forceinline__ void run_dir(float* lds,
        const v2f (&wh)[3][8], const v2f (&wx)[3][8], const v2f (&wp)[10],
        const float* __restrict__ bih, const float* __restrict__ bhh,
        const float* __restrict__ bp, int w, int lane, int ln, int& par) {
    float* st = lds + OFF_ST;
    const unsigned* succm = (const unsigned*)(lds + OFF_MASK);
    const unsigned* predm = succm + 32;

    const float b0s = bih[ln] + bhh[ln];
    const float b1s = bih[60 + ln] + bhh[60 + ln];
    const float b2i = bih[120 + ln];
    const float b2h = bhh[120 + ln];
    const float bpv = bp[ln];

    for (int s = 0; s < Nn; ++s) {
        const int t = FWD ? s : (Nn - 1 - s);

        // ---- finalize rho[t]: cooperative proj over [h(60); z(10); dz(10)] ----
        v2f pa = {0.f, 0.f};
        const v2f* xb = (w < 3) ? ((const v2f*)(st + t * 64) + 10 * w)
                                : ((const v2f*)(lds + OFF_ZDZ + t * 20));
#pragma unroll
        for (int p = 0; p < 10; ++p)
            pa = __builtin_elementwise_fma(wp[p], xb[p], pa);
        lds[OFF_RP + (par * 4 + w) * 64 + lane] = pa.x + pa.y;
        __syncthreads();
        float sum = lds[OFF_RP + (par * 4 + 0) * 64 + lane]
                  + lds[OFF_RP + (par * 4 + 1) * 64 + lane]
                  + lds[OFF_RP + (par * 4 + 2) * 64 + lane]
                  + lds[OFF_RP + (par * 4 + 3) * 64 + lane] + bpv;
        par ^= 1;
        const float rho = FWD ? tanh_f(sum) : sum;
        if (lane < SP) st[t * 64 + lane] = rho;   // replicated identical write
        // (own-wave LDS write->read below is in-order; no barrier needed)

        // ---- GRU pushes, gated by has[t]; successors batched 4 per round ----
        const float hb = lds[OFF_HAS + t];
        unsigned m = (hb != 0.f) ? (FWD ? succm[t] : predm[t]) : 0u;
        if (m) {
            float gi0, gi1, gi2;      // x-side slice of rho[t], hoisted per node
            matvec3(wx, (const v2f*)(st + t * 64) + 8 * w, gi0, gi1, gi2);
            while (m) {
                int i0 = __ffs(m) - 1; m &= m - 1u;
                int i1 = -1, i2 = -1, i3 = -1, cnt = 1;
                if (m) { i1 = __ffs(m) - 1; m &= m - 1u; ++cnt;
                    if (m) { i2 = __ffs(m) - 1; m &= m - 1u; ++cnt;
                        if (m) { i3 = __ffs(m) - 1; m &= m - 1u; ++cnt; } } }
                {
                    float g0, g1, g2;
                    matvec3(wh, (const v2f*)(st + i0 * 64) + 8 * w, g0, g1, g2);
                    float4 q = {gi0 + g0, gi1 + g1, gi2, g2};
                    *(float4*)(lds + OFF_PART + ((0 * 4 + w) * 64 + lane) * 4) = q;
                }
                if (cnt > 1) {
                    float g0, g1, g2;
                    matvec3(wh, (const v2f*)(st + i1 * 64) + 8 * w, g0, g1, g2);
                    float4 q = {gi0 + g0, gi1 + g1, gi2, g2};
                    *(float4*)(lds + OFF_PART + ((1 * 4 + w) * 64 + lane) * 4) = q;
                }
                if (cnt > 2) {
                    float g0, g1, g2;
                    matvec3(wh, (const v2f*)(st + i2 * 64) + 8 * w, g0, g1, g2);
                    float4 q = {gi0 + g0, gi1 + g1, gi2, g2};
                    *(float4*)(lds + OFF_PART + ((2 * 4 + w) * 64 + lane) * 4) = q;
                }
                if (cnt > 3) {
                    float g0, g1, g2;
                    matvec3(wh, (const v2f*)(st + i3 * 64) + 8 * w, g0, g1, g2);
                    float4 q = {gi0 + g0, gi1 + g1, gi2, g2};
                    *(float4*)(lds + OFF_PART + ((3 * 4 + w) * 64 + lane) * 4) = q;
                }
                __syncthreads();
                if (w < cnt) {        // wave w finalizes successor #w of chunk
                    const int it = (w == 0) ? i0 : (w == 1) ? i1 : (w == 2) ? i2 : i3;
                    const float4 q0 = *(const float4*)(lds + OFF_PART + ((w * 4 + 0) * 64 + lane) * 4);
                    const float4 q1 = *(const float4*)(lds + OFF_PART + ((w * 4 + 1) * 64 + lane) * 4);
                    const float4 q2 = *(const float4*)(lds + OFF_PART + ((w * 4 + 2) * 64 + lane) * 4);
                    const float4 q3 = *(const float4*)(lds + OFF_PART + ((w * 4 + 3) * 64 + lane) * 4);
                    const float a0  = q0.x + q1.x + q2.x + q3.x + b0s;
                    const float a1  = q0.y + q1.y + q2.y + q3.y + b1s;
                    const float a2i = q0.z + q1.z + q2.z + q3.z + b2i;
                    const float a2h = q0.w + q1.w + q2.w + q3.w + b2h;
                    const float r = sigm(a0);
                    const float u = sigm(a1);
                    const float n = tanh_f(fmaf(r, a2h, a2i));
                    const float hold = st[it * 64 + lane];   // pre-update h
                    const float hnew = fmaf(u, hold - n, n);
                    if (lane < SP) st[it * 64 + lane] = hnew;
                }
                __syncthreads();
            }
        }
    }

    // ---- alpha scan (single GRU chain; wave 0 finalizes) ----
    float* ah = lds + (FWD ? OFF_AF : OFF_AB);
    ah[lane] = 0.f;                               // replicated identical write
    const int acn = FWD ? 5 : 6;
    for (int s2 = 0; s2 < acn; ++s2) {
        const int i = FWD ? (Nn - 5 + s2) : (5 - s2);
        if (lds[OFF_HAS + i] == 0.f) continue;    // block-uniform skip
        float gi0, gi1, gi2, g0, g1, g2;
        matvec3(wx, (const v2f*)(st + i * 64) + 8 * w, gi0, gi1, gi2);
        matvec3(wh, (const v2f*)(ah) + 8 * w, g0, g1, g2);
        float4 q = {gi0 + g0, gi1 + g1, gi2, g2};
        *(float4*)(lds + OFF_PART + (w * 64 + lane) * 4) = q;
        __syncthreads();
        if (w == 0) {
            const float4 q0 = *(const float4*)(lds + OFF_PART + ((0 * 64) + lane) * 4);
            const float4 q1 = *(const float4*)(lds + OFF_PART + ((1 * 64) + lane) * 4);
            const float4 q2 = *(const float4*)(lds + OFF_PART + ((2 * 64) + lane) * 4);
            const float4 q3 = *(const float4*)(lds + OFF_PART + ((3 * 64) + lane) * 4);
            const float a0  = q0.x + q1.x + q2.x + q3.x + b0s;
            const float a1  = q0.y + q1.y + q2.y + q3.y + b1s;
            const float a2i = q0.z + q1.z + q2.z + q3.z + b2i;
            const float a2h = q0.w + q1.w + q2.w + q3.w + b2h;
            const float r = sigm(a0);
            const float u = sigm(a1);
            const float n = tanh_f(fmaf(r, a2h, a2i));
            const float hold = ah[lane];
            const float hnew = fmaf(u, hold - n, n);
            if (lane < SP) ah[lane] = hnew;
        }
        __syncthreads();
    }
}

__device__ void run_heads(float* lds, int b, int lane, float* __restrict__ out) {
    const float* aF = lds + OFF_AF;
    const float* aB = lds + OFF_AB;

    float o = 0.f;
    if (lane < NA) {
        o = lds[OFF_BA + lane];
        const float* wa = lds + OFF_WA + lane * 120;
#pragma unroll
        for (int k = 0; k < SP; ++k) o = fmaf(wa[k], aF[k], o);
#pragma unroll
        for (int k = 0; k < SP; ++k) o = fmaf(wa[60 + k], aB[k], o);
        lds[OFF_OS + lane] = o;
    } else if (lane == NA) {
        float v = lds[OFF_BC];
        const float* wc = lds + OFF_WC;
#pragma unroll
        for (int k = 0; k < SP; ++k) v = fmaf(wc[k], aF[k], v);
#pragma unroll
        for (int k = 0; k < SP; ++k) v = fmaf(wc[60 + k], aB[k], v);
        out[Bc * NA + Bc * NR * Nn + b] = v;
    }
    __builtin_amdgcn_wave_barrier();

    if (lane < NA) {
        const float* os = lds + OFF_OS;
        float mx = os[0];
#pragma unroll
        for (int j = 1; j < NA; ++j) mx = fmaxf(mx, os[j]);
        float sum = 0.f;
#pragma unroll
        for (int j = 0; j < NA; ++j) sum += __expf(os[j] - mx);
        out[b * NA + lane] = __expf(o - mx) / sum;
    }

    if (lane < Nn) {
        const int i = lane;
        const float mk = lds[OFF_HAS + i];
        float p[NR];
        float mx = -1e30f;
#pragma unroll
        for (int c = 0; c < NR; ++c) {
            const float v = (mk != 0.f)
                ? (lds[OFF_PSI + i * 8 + c] + lds[OFF_BU + c])
                : -60.0f;
            p[c] = v;
            mx = fmaxf(mx, v);
        }
        float sum = 0.f;
#pragma unroll
        for (int c = 0; c < NR; ++c) { p[c] = __expf(p[c] - mx); sum += p[c]; }
        const float inv = 1.0f / sum;
#pragma unroll
        for (int c = 0; c < NR; ++c)
            out[Bc * NA + b * (NR * Nn) + c * Nn + i] = p[c] * inv;
    }
}

__global__ __launch_bounds__(256, 2)
void dn_kernel(const float* __restrict__ has, const float* __restrict__ z,
               const float* __restrict__ dz, const unsigned* __restrict__ adjw,
               const float* __restrict__ bih_f, const float* __restrict__ bhh_f,
               const float* __restrict__ bih_b, const float* __restrict__ bhh_b,
               const float* __restrict__ bf, const float* __restrict__ bb,
               const float* __restrict__ Wa, const float* __restrict__ ba,
               const float* __restrict__ Wc, const float* __restrict__ bc,
               const float* __restrict__ Wu, const float* __restrict__ bu,
               const float* __restrict__ ws, float* __restrict__ out) {
    __shared__ float lds[LDS_FLOATS];
    const int tid = threadIdx.x;
    const int lane = tid & 63;
    const int w = tid >> 6;
    const int b = blockIdx.x;
    const int ln = (lane < SP) ? lane : (SP - 1);   // clamp for bias loads

    unsigned* succm = (unsigned*)(lds + OFF_MASK);
    unsigned* predm = succm + 32;
    unsigned* flags = predm + 32;

    if (tid < 4) flags[tid] = 0u;
    __syncthreads();

    // ---- adj dtype detection (first 256 words only) ----
    {
        unsigned ff = 0u, fb = 0u;
        for (int i = tid; i < 256; i += 256) {
            const unsigned v = adjw[i];
            ff |= (v == 0x3f800000u) ? 1u : 0u;
            fb |= (v > 1u && v != 0x3f800000u) ? 1u : 0u;
        }
        if (ff) atomicOr(&flags[0], 1u);
        if (fb) atomicOr(&flags[1], 1u);
    }

    // ---- stage head weights, has, z/dz; zero state array ----
    for (int i = tid; i < 840; i += 256) lds[OFF_WU + i] = Wu[i];
    for (int i = tid; i < 600; i += 256) lds[OFF_WA + i] = Wa[i];
    if (tid < 120) lds[OFF_WC + tid] = Wc[tid];
    if (tid < NR) lds[OFF_BU + tid] = bu[tid];
    if (tid < NA) lds[OFF_BA + tid] = ba[tid];
    if (tid == 0) lds[OFF_BC] = bc[0];
    if (tid < Nn) lds[OFF_HAS + tid] = has[b * 32 + tid];
    for (int i = tid; i < Nn * 20; i += 256) {
        const int t = i / 20, k = i - t * 20;
        lds[OFF_ZDZ + i] = (k < 10) ? z[(b * Nn + t) * 10 + k]
                                    : dz[(b * Nn + t) * 10 + (k - 10)];
    }
    for (int i = tid; i < Nn * 64; i += 256) lds[OFF_ST + i] = 0.f;
    __syncthreads();

    // ---- adjacency bitmasks ----
    const int mode = flags[0] ? 2 : (flags[1] ? 1 : 0);
    if (tid < 32) {
        unsigned sm = 0u;
        for (int c = 0; c < 32; ++c) sm |= adj_nz(adjw, mode, tid, c) << c;
        succm[tid] = sm;
    } else if (tid < 64) {
        const int c = tid - 32;
        unsigned pm = 0u;
        for (int r = 0; r < 32; ++r) pm |= adj_nz(adjw, mode, r, c) << r;
        predm[c] = pm;
    }
    __syncthreads();

    // ---- opaque 1.0f (for wx/wp; wh uses the volatile-asm pin) ----
    float one = 1.0f;
    asm volatile("" : "+v"(one));
    const v2f onev = {one, one};

    int par = 0;
    v2f wh[3][8], wx[3][8], wp[10];

    // ---- forward direction ----
    load_w(ws, 0, w, lane, onev, wh, wx, wp);
    run_dir<1>(lds, wh, wx, wp, bih_f, bhh_f, bf, w, lane, ln, par);
    __syncthreads();

    // ---- psi pass 1 (fwd half) while rho_f still in ST ----
    if (tid < Nn * NR) {
        const int i = tid / NR, c = tid - i * NR;
        const float* wu = lds + OFF_WU + c * 120;
        const float* sf = lds + OFF_ST + i * 64;
        float acc = 0.f;
#pragma unroll
        for (int k = 0; k < SP; ++k) acc = fmaf(wu[k], sf[k], acc);
        lds[OFF_PSI + i * 8 + c] = acc;
    }
    __syncthreads();

    // ---- re-zero ST for backward direction ----
    for (int i = tid; i < Nn * 64; i += 256) lds[OFF_ST + i] = 0.f;
    __syncthreads();

    // ---- backward direction ----
    load_w(ws, 1, w, lane, onev, wh, wx, wp);
    run_dir<0>(lds, wh, wx, wp, bih_b, bhh_b, bb, w, lane, ln, par);
    __syncthreads();

    // ---- psi pass 2 (bwd half) ----
    if (tid < Nn * NR) {
        const int i = tid / NR, c = tid - i * NR;
        const float* wu = lds + OFF_WU + c * 120 + 60;
        const float* sb = lds + OFF_ST + i * 64;
        float acc = 0.f;
#pragma unroll
        for (int k = 0; k < SP; ++k) acc = fmaf(wu[k], sb[k], acc);
        lds[OFF_PSI + i * 8 + c] += acc;
    }
    __syncthreads();

    if (w == 0) run_heads(lds, b, lane, out);
}

}  // namespace

extern "C" void kernel_launch(void* const* d_in, const int* in_sizes, int n_in,
                              void* d_out, int out_size, void* d_ws, size_t ws_size,
                              hipStream_t stream) {
    (void)in_sizes; (void)n_in; (void)out_size; (void)ws_size;
    const float* has     = (const float*)d_in[0];
    const float* z       = (const float*)d_in[1];
    const float* dz      = (const float*)d_in[2];
    const unsigned* adjw = (const unsigned*)d_in[3];
    const float* Wih_f   = (const float*)d_in[4];
    const float* Whh_f   = (const float*)d_in[5];
    const float* bih_f   = (const float*)d_in[6];
    const float* bhh_f   = (const float*)d_in[7];
    const float* Wih_b   = (const float*)d_in[8];
    const float* Whh_b   = (const float*)d_in[9];
    const float* bih_b   = (const float*)d_in[10];
    const float* bhh_b   = (const float*)d_in[11];
    const float* Wf      = (const float*)d_in[12];
    const float* bf      = (const float*)d_in[13];
    const float* Wb      = (const float*)d_in[14];
    const float* bb      = (const float*)d_in[15];
    const float* Wa      = (const float*)d_in[16];
    const float* ba      = (const float*)d_in[17];
    const float* Wc      = (const float*)d_in[18];
    const float* bc      = (const float*)d_in[19];
    const float* Wu      = (const float*)d_in[20];
    const float* bu      = (const float*)d_in[21];
    float* out = (float*)d_out;
    float* ws  = (float*)d_ws;   // needs WS_TOTAL*4 = 237.6KB of scratch

    pack_kernel<<<(WS_TOTAL + 255) / 256, 256, 0, stream>>>(
        Whh_f, Wih_f, Wf, Whh_b, Wih_b, Wb, ws);

    dn_kernel<<<Bc, 256, 0, stream>>>(
        has, z, dz, adjw,
        bih_f, bhh_f, bih_b, bhh_b, bf, bb,
        Wa, ba, Wc, bc, Wu, bu, ws, out);
}

// Round 11
// 345.689 us; speedup vs baseline: 1.2927x; 1.0758x over previous
//
#include <hip/hip_runtime.h>

// DesignerNetwork: B=1024 batch-independent graph-GRU network.
// Round 11: TWO samples per block, processed by the same threads. adj is
// batch-shared, so both samples follow one barrier/round schedule; has is
// folded as a multiplier (h + m*(h2-h), exact for m in {0,1}) instead of a
// skip (skip only if both samples' m==0). Each weight slice fetched per
// round now feeds 2x the work -> per-sample barriers and L1 weight traffic
// halve. Grid 512 = exactly 2 blocks/CU resident (LDS 66.8KB). Launch
// bounds stay (256,2) - min_waves>=4 makes the allocator spill (r4/r9).

namespace {

typedef float v2f __attribute__((ext_vector_type(2)));

constexpr int Bc = 1024;   // batch
constexpr int Nn = 32;     // nodes
constexpr int SP = 60;     // S_PHI == S_RHO
constexpr int NA = 5;      // actions
constexpr int NR = 7;      // roles

// ---- d_ws float layout (packed weights) ----
// WHH: [dir2][gate3][lane64][wave4][16f]  = 24576 floats @ 0
// WIH: same                               = 24576 floats @ 24576
// WP : [dir2][lane64][wave4][20f]         = 10240 floats @ 49152
constexpr int WS_WIH = 24576;
constexpr int WS_WP  = 49152;
constexpr int WS_TOTAL = 59392;
constexpr int DSTRIDE_G = 12288;
constexpr int DSTRIDE_P = 5120;

// ---- LDS layout (float offsets) ----
constexpr int OFF_ST   = 0;        // states [2][32][64] = 4096
constexpr int OFF_RP   = 4096;     // rho partials [2par][2s][4w][64] = 1024
constexpr int OFF_PART = 5120;     // chunk partials [2s][4slot][4w][64][4] = 8192
constexpr int OFF_ZDZ  = 13312;    // z/dz [2][32][20] = 1280
constexpr int OFF_PSI  = 14592;    // psi raw [2][32][8] = 512
constexpr int OFF_WU   = 15104;    // Wu 7x120
constexpr int OFF_WA   = 15944;    // Wa 5x120
constexpr int OFF_WC   = 16544;    // Wc 120
constexpr int OFF_BA   = 16664;    // ba (pad 8)
constexpr int OFF_BU   = 16672;    // bu (pad 8)
constexpr int OFF_BC   = 16680;    // bc (pad 4)
constexpr int OFF_HAS  = 16684;    // has [2][32]
constexpr int OFF_AF   = 16748;    // alpha_f [2][64]
constexpr int OFF_AB   = 16876;    // alpha_b [2][64]
constexpr int OFF_OS   = 17004;    // omega scratch [2][8]
constexpr int OFF_MASK = 17020;    // uints: succ[32] pred[32] flags[4]
constexpr int LDS_FLOATS = OFF_MASK + 68 + 8;   // 17096 floats = 66.8KB

__device__ __forceinline__ float sigm(float x) {
    return 1.0f / (1.0f + __expf(-x));
}

__device__ __forceinline__ float tanh_f(float x) {
    float e = __expf(fminf(2.0f * x, 80.0f));
    return (e - 1.0f) / (e + 1.0f);
}

// adj may arrive as int32 (0/1), packed uint8 bool, or float32. mode: 0/1/2.
__device__ __forceinline__ unsigned adj_nz(const unsigned* a, int mode, int r, int c) {
    const int idx = r * 32 + c;
    unsigned v = (mode == 1) ? ((a[idx >> 2] >> (8 * (idx & 3))) & 0xffu) : a[idx];
    return v != 0u ? 1u : 0u;
}

// 3-gate dot of weight slice with 8-v2f x slice (pads are zero both sides).
__device__ __forceinline__ void matvec3(const v2f (&W)[3][8], const v2f* x,
                                        float& r0, float& r1, float& r2) {
    v2f a0 = {0.f, 0.f}, a1 = {0.f, 0.f}, a2 = {0.f, 0.f};
#pragma unroll
    for (int p = 0; p < 8; ++p) {
        const v2f xp = x[p];
        a0 = __builtin_elementwise_fma(W[0][p], xp, a0);
        a1 = __builtin_elementwise_fma(W[1][p], xp, a1);
        a2 = __builtin_elementwise_fma(W[2][p], xp, a2);
    }
    r0 = a0.x + a0.y; r1 = a1.x + a1.y; r2 = a2.x + a2.y;
}

__device__ __forceinline__ void load_w(const float* __restrict__ ws, int d,
        int w, int lane, v2f onev,
        v2f (&wh)[3][8], v2f (&wx)[3][8], v2f (&wp)[10]) {
    const v2f* WH = (const v2f*)(ws + d * DSTRIDE_G + ((lane * 4 + w) << 4));
    const v2f* WX = (const v2f*)(ws + WS_WIH + d * DSTRIDE_G + ((lane * 4 + w) << 4));
    const v2f* WPp = (const v2f*)(ws + WS_WP + d * DSTRIDE_P + (lane * 4 + w) * 20);
#pragma unroll
    for (int g = 0; g < 3; ++g)
#pragma unroll
        for (int p = 0; p < 8; ++p) {
            wh[g][p] = WH[g * 2048 + p] * onev;
            wx[g][p] = WX[g * 2048 + p] * onev;
        }
#pragma unroll
    for (int p = 0; p < 10; ++p) wp[p] = WPp[p] * onev;
}

// ---- weight pre-pack kernel ----
__global__ void pack_kernel(const float* __restrict__ Whh_f, const float* __restrict__ Wih_f,
                            const float* __restrict__ Wf,
                            const float* __restrict__ Whh_b, const float* __restrict__ Wih_b,
                            const float* __restrict__ Wb, float* __restrict__ ws) {
    const int idx = blockIdx.x * 256 + threadIdx.x;
    if (idx < 2 * 24576) {
        const int which = idx / 24576;      // 0=WHH, 1=WIH
        int r = idx % 24576;
        const int j = r & 15; r >>= 4;
        const int w = r & 3;  r >>= 2;
        const int lane = r & 63; r >>= 6;
        const int g = r % 3;
        const int d = r / 3;
        const int k = 16 * w + j;
        const float* src = which ? (d ? Wih_b : Wih_f) : (d ? Whh_b : Whh_f);
        ws[idx] = (lane < 60 && k < 60) ? src[(g * 60 + lane) * 60 + k] : 0.f;
    } else if (idx < WS_TOTAL) {
        int r = idx - WS_WP;
        const int jj = r % 20; r /= 20;
        const int w = r & 3;  r >>= 2;
        const int lane = r & 63;
        const int d = r >> 6;
        const float* src = d ? Wb : Wf;
        const int pk = (w < 3) ? 20 * w : 60;
        ws[idx] = (lane < 60) ? src[lane * 80 + pk + jj] : 0.f;
    }
}

// GRU finalize from 4 partial float4s for one (sample, successor), with
// has-multiplier fold: hnew = hold + m*(h2 - hold).
__device__ __forceinline__ void gru_fin(float* lds, int s, int slot, int lane,
        float b0s, float b1s, float b2i, float b2h,
        float* hrow, float m, bool act) {
    const int base = OFF_PART + ((s * 4 + slot) * 4) * 256;
    const float4 q0 = *(const float4*)(lds + base + (0 * 64 + lane) * 4);
    const float4 q1 = *(const float4*)(lds + base + (1 * 64 + lane) * 4);
    const float4 q2 = *(const float4*)(lds + base + (2 * 64 + lane) * 4);
    const float4 q3 = *(const float4*)(lds + base + (3 * 64 + lane) * 4);
    const float a0  = q0.x + q1.x + q2.x + q3.x + b0s;
    const float a1  = q0.y + q1.y + q2.y + q3.y + b1s;
    const float a2i = q0.z + q1.z + q2.z + q3.z + b2i;
    const float a2h = q0.w + q1.w + q2.w + q3.w + b2h;
    const float r = sigm(a0);
    const float u = sigm(a1);
    const float n = tanh_f(fmaf(r, a2h, a2i));
    const float hold = hrow[lane];
    const float h2 = fmaf(u, hold - n, n);
    const float hnew = fmaf(m, h2 - hold, hold);
    if (act) hrow[lane] = hnew;
}

template <int FWD>
__device__ __forceinline__ void run_dir(float* lds,
        const v2f (&wh)[3][8], const v2f (&wx)[3][8], const v2f (&wp)[10],
        const float* __restrict__ bih, const float* __restrict__ bhh,
        const float* __restrict__ bp, int w, int lane, int ln, int& par) {
    float* st0 = lds + OFF_ST;
    float* st1 = lds + OFF_ST + 2048;
    const unsigned* succm = (const unsigned*)(lds + OFF_MASK);
    const unsigned* predm = succm + 32;
    const bool act = lane < SP;

    const float b0s = bih[ln] + bhh[ln];
    const float b1s = bih[60 + ln] + bhh[60 + ln];
    const float b2i = bih[120 + ln];
    const float b2h = bhh[120 + ln];
    const float bpv = bp[ln];

    for (int s = 0; s < Nn; ++s) {
        const int t = FWD ? s : (Nn - 1 - s);

        // ---- finalize rho[t] for BOTH samples ----
        v2f pa0 = {0.f, 0.f}, pa1 = {0.f, 0.f};
        const v2f* xb0 = (w < 3) ? ((const v2f*)(st0 + t * 64) + 10 * w)
                                 : ((const v2f*)(lds + OFF_ZDZ + t * 20));
        const v2f* xb1 = (w < 3) ? ((const v2f*)(st1 + t * 64) + 10 * w)
                                 : ((const v2f*)(lds + OFF_ZDZ + 640 + t * 20));
#pragma unroll
        for (int p = 0; p < 10; ++p) {
            pa0 = __builtin_elementwise_fma(wp[p], xb0[p], pa0);
            pa1 = __builtin_elementwise_fma(wp[p], xb1[p], pa1);
        }
        lds[OFF_RP + ((par * 2 + 0) * 4 + w) * 64 + lane] = pa0.x + pa0.y;
        lds[OFF_RP + ((par * 2 + 1) * 4 + w) * 64 + lane] = pa1.x + pa1.y;
        __syncthreads();
        float sum0 = lds[OFF_RP + ((par * 2) * 4 + 0) * 64 + lane]
                   + lds[OFF_RP + ((par * 2) * 4 + 1) * 64 + lane]
                   + lds[OFF_RP + ((par * 2) * 4 + 2) * 64 + lane]
                   + lds[OFF_RP + ((par * 2) * 4 + 3) * 64 + lane] + bpv;
        float sum1 = lds[OFF_RP + ((par * 2 + 1) * 4 + 0) * 64 + lane]
                   + lds[OFF_RP + ((par * 2 + 1) * 4 + 1) * 64 + lane]
                   + lds[OFF_RP + ((par * 2 + 1) * 4 + 2) * 64 + lane]
                   + lds[OFF_RP + ((par * 2 + 1) * 4 + 3) * 64 + lane] + bpv;
        par ^= 1;
        const float rho0 = FWD ? tanh_f(sum0) : sum0;
        const float rho1 = FWD ? tanh_f(sum1) : sum1;
        if (act) { st0[t * 64 + lane] = rho0; st1[t * 64 + lane] = rho1; }
        // (own-wave LDS write->read below is in-order; no barrier needed)

        // ---- GRU pushes to successors, has folded as multiplier ----
        const float m0 = lds[OFF_HAS + t];
        const float m1 = lds[OFF_HAS + 32 + t];
        unsigned mk = (m0 != 0.f || m1 != 0.f) ? (FWD ? succm[t] : predm[t]) : 0u;
        if (mk) {
            float gA0, gA1, gA2, gB0, gB1, gB2;   // x-side per sample, per node
            matvec3(wx, (const v2f*)(st0 + t * 64) + 8 * w, gA0, gA1, gA2);
            matvec3(wx, (const v2f*)(st1 + t * 64) + 8 * w, gB0, gB1, gB2);
            while (mk) {
                int i0 = __ffs(mk) - 1; mk &= mk - 1u;
                int i1 = -1, i2 = -1, i3 = -1, cnt = 1;
                if (mk) { i1 = __ffs(mk) - 1; mk &= mk - 1u; ++cnt;
                    if (mk) { i2 = __ffs(mk) - 1; mk &= mk - 1u; ++cnt;
                        if (mk) { i3 = __ffs(mk) - 1; mk &= mk - 1u; ++cnt; } } }
                const int ii[4] = {i0, i1, i2, i3};
#pragma unroll
                for (int j = 0; j < 4; ++j) {
                    if (j >= cnt) break;
                    float g0, g1, g2;
                    matvec3(wh, (const v2f*)(st0 + ii[j] * 64) + 8 * w, g0, g1, g2);
                    float4 q = {gA0 + g0, gA1 + g1, gA2, g2};
                    *(float4*)(lds + OFF_PART + ((0 * 4 + j) * 4 + w) * 256 + lane * 4) = q;
                    matvec3(wh, (const v2f*)(st1 + ii[j] * 64) + 8 * w, g0, g1, g2);
                    float4 q2v = {gB0 + g0, gB1 + g1, gB2, g2};
                    *(float4*)(lds + OFF_PART + ((1 * 4 + j) * 4 + w) * 256 + lane * 4) = q2v;
                }
                __syncthreads();
                if (w < cnt) {        // wave w finalizes successor #w, both samples
                    const int it = ii[w];
                    gru_fin(lds, 0, w, lane, b0s, b1s, b2i, b2h, st0 + it * 64, m0, act);
                    gru_fin(lds, 1, w, lane, b0s, b1s, b2i, b2h, st1 + it * 64, m1, act);
                }
                __syncthreads();
            }
        }
    }

    // ---- alpha scan (both samples; waves 0/1 finalize) ----
    float* ah0 = lds + (FWD ? OFF_AF : OFF_AB);
    float* ah1 = ah0 + 64;
    ah0[lane] = 0.f; ah1[lane] = 0.f;             // replicated identical write
    const int acn = FWD ? 5 : 6;
    for (int s2 = 0; s2 < acn; ++s2) {
        const int i = FWD ? (Nn - 5 + s2) : (5 - s2);
        const float m0 = lds[OFF_HAS + i];
        const float m1 = lds[OFF_HAS + 32 + i];
        if (m0 == 0.f && m1 == 0.f) continue;     // block-uniform skip
        float gA0, gA1, gA2, gB0, gB1, gB2, g0, g1, g2;
        matvec3(wx, (const v2f*)(st0 + i * 64) + 8 * w, gA0, gA1, gA2);
        matvec3(wh, (const v2f*)(ah0) + 8 * w, g0, g1, g2);
        float4 q = {gA0 + g0, gA1 + g1, gA2, g2};
        *(float4*)(lds + OFF_PART + ((0 * 4 + 0) * 4 + w) * 256 + lane * 4) = q;
        matvec3(wx, (const v2f*)(st1 + i * 64) + 8 * w, gB0, gB1, gB2);
        matvec3(wh, (const v2f*)(ah1) + 8 * w, g0, g1, g2);
        float4 q2v = {gB0 + g0, gB1 + g1, gB2, g2};
        *(float4*)(lds + OFF_PART + ((1 * 4 + 0) * 4 + w) * 256 + lane * 4) = q2v;
        __syncthreads();
        if (w == 0)      gru_fin(lds, 0, 0, lane, b0s, b1s, b2i, b2h, ah0, m0, act);
        else if (w == 1) gru_fin(lds, 1, 0, lane, b0s, b1s, b2i, b2h, ah1, m1, act);
        __syncthreads();
    }
}

__device__ void run_heads(float* lds, int s, int b, int lane, float* __restrict__ out) {
    const float* aF = lds + OFF_AF + s * 64;
    const float* aB = lds + OFF_AB + s * 64;

    float o = 0.f;
    if (lane < NA) {
        o = lds[OFF_BA + lane];
        const float* wa = lds + OFF_WA + lane * 120;
#pragma unroll
        for (int k = 0; k < SP; ++k) o = fmaf(wa[k], aF[k], o);
#pragma unroll
        for (int k = 0; k < SP; ++k) o = fmaf(wa[60 + k], aB[k], o);
        lds[OFF_OS + s * 8 + lane] = o;
    } else if (lane == NA) {
        float v = lds[OFF_BC];
        const float* wc = lds + OFF_WC;
#pragma unroll
        for (int k = 0; k < SP; ++k) v = fmaf(wc[k], aF[k], v);
#pragma unroll
        for (int k = 0; k < SP; ++k) v = fmaf(wc[60 + k], aB[k], v);
        out[Bc * NA + Bc * NR * Nn + b] = v;
    }
    __builtin_amdgcn_wave_barrier();

    if (lane < NA) {
        const float* os = lds + OFF_OS + s * 8;
        float mx = os[0];
#pragma unroll
        for (int j = 1; j < NA; ++j) mx = fmaxf(mx, os[j]);
        float sum = 0.f;
#pragma unroll
        for (int j = 0; j < NA; ++j) sum += __expf(os[j] - mx);
        out[b * NA + lane] = __expf(o - mx) / sum;
    }

    if (lane < Nn) {
        const int i = lane;
        const float mkk = lds[OFF_HAS + s * 32 + i];
        float p[NR];
        float mx = -1e30f;
#pragma unroll
        for (int c = 0; c < NR; ++c) {
            const float v = (mkk != 0.f)
                ? (lds[OFF_PSI + s * 256 + i * 8 + c] + lds[OFF_BU + c])
                : -60.0f;
            p[c] = v;
            mx = fmaxf(mx, v);
        }
        float sum = 0.f;
#pragma unroll
        for (int c = 0; c < NR; ++c) { p[c] = __expf(p[c] - mx); sum += p[c]; }
        const float inv = 1.0f / sum;
#pragma unroll
        for (int c = 0; c < NR; ++c)
            out[Bc * NA + b * (NR * Nn) + c * Nn + i] = p[c] * inv;
    }
}

__global__ __launch_bounds__(256, 2)
void dn_kernel(const float* __restrict__ has, const float* __restrict__ z,
               const float* __restrict__ dz, const unsigned* __restrict__ adjw,
               const float* __restrict__ bih_f, const float* __restrict__ bhh_f,
               const float* __restrict__ bih_b, const float* __restrict__ bhh_b,
               const float* __restrict__ bf, const float* __restrict__ bb,
               const float* __restrict__ Wa, const float* __restrict__ ba,
               const float* __restrict__ Wc, const float* __restrict__ bc,
               const float* __restrict__ Wu, const float* __restrict__ bu,
               const float* __restrict__ ws, float* __restrict__ out) {
    __shared__ float lds[LDS_FLOATS];
    const int tid = threadIdx.x;
    const int lane = tid & 63;
    const int w = tid >> 6;
    const int b0 = blockIdx.x * 2;
    const int ln = (lane < SP) ? lane : (SP - 1);   // clamp for bias loads

    unsigned* succm = (unsigned*)(lds + OFF_MASK);
    unsigned* predm = succm + 32;
    unsigned* flags = predm + 32;

    if (tid < 4) flags[tid] = 0u;
    __syncthreads();

    // ---- adj dtype detection (first 256 words only) ----
    {
        unsigned ff = 0u, fb = 0u;
        for (int i = tid; i < 256; i += 256) {
            const unsigned v = adjw[i];
            ff |= (v == 0x3f800000u) ? 1u : 0u;
            fb |= (v > 1u && v != 0x3f800000u) ? 1u : 0u;
        }
        if (ff) atomicOr(&flags[0], 1u);
        if (fb) atomicOr(&flags[1], 1u);
    }

    // ---- stage head weights, has, z/dz (both samples); zero states ----
    for (int i = tid; i < 840; i += 256) lds[OFF_WU + i] = Wu[i];
    for (int i = tid; i < 600; i += 256) lds[OFF_WA + i] = Wa[i];
    if (tid < 120) lds[OFF_WC + tid] = Wc[tid];
    if (tid < NR) lds[OFF_BU + tid] = bu[tid];
    if (tid < NA) lds[OFF_BA + tid] = ba[tid];
    if (tid == 0) lds[OFF_BC] = bc[0];
    if (tid < 64) lds[OFF_HAS + tid] = has[(b0 + (tid >> 5)) * 32 + (tid & 31)];
    for (int i = tid; i < 2 * Nn * 20; i += 256) {
        const int ss = i / 640, r = i - ss * 640;
        const int t = r / 20, k = r - t * 20;
        lds[OFF_ZDZ + i] = (k < 10) ? z[((b0 + ss) * Nn + t) * 10 + k]
                                    : dz[((b0 + ss) * Nn + t) * 10 + (k - 10)];
    }
    for (int i = tid; i < 2 * Nn * 64; i += 256) lds[OFF_ST + i] = 0.f;
    __syncthreads();

    // ---- adjacency bitmasks ----
    const int mode = flags[0] ? 2 : (flags[1] ? 1 : 0);
    if (tid < 32) {
        unsigned sm = 0u;
        for (int c = 0; c < 32; ++c) sm |= adj_nz(adjw, mode, tid, c) << c;
        succm[tid] = sm;
    } else if (tid < 64) {
        const int c = tid - 32;
        unsigned pm = 0u;
        for (int r = 0; r < 32; ++r) pm |= adj_nz(adjw, mode, r, c) << r;
        predm[c] = pm;
    }
    __syncthreads();

    // ---- opaque 1.0f (discourages rematerialization of weight loads) ----
    float one = 1.0f;
    asm volatile("" : "+v"(one));
    const v2f onev = {one, one};

    int par = 0;
    v2f wh[3][8], wx[3][8], wp[10];

    // ---- forward direction ----
    load_w(ws, 0, w, lane, onev, wh, wx, wp);
    run_dir<1>(lds, wh, wx, wp, bih_f, bhh_f, bf, w, lane, ln, par);
    __syncthreads();

    // ---- psi pass 1 (fwd half), both samples ----
    if (tid < Nn * NR) {
        const int i = tid / NR, c = tid - i * NR;
        const float* wu = lds + OFF_WU + c * 120;
        const float* s0 = lds + OFF_ST + i * 64;
        const float* s1 = lds + OFF_ST + 2048 + i * 64;
        float a0 = 0.f, a1 = 0.f;
#pragma unroll
        for (int k = 0; k < SP; ++k) {
            a0 = fmaf(wu[k], s0[k], a0);
            a1 = fmaf(wu[k], s1[k], a1);
        }
        lds[OFF_PSI + i * 8 + c] = a0;
        lds[OFF_PSI + 256 + i * 8 + c] = a1;
    }
    __syncthreads();

    // ---- re-zero states for backward direction ----
    for (int i = tid; i < 2 * Nn * 64; i += 256) lds[OFF_ST + i] = 0.f;
    __syncthreads();

    // ---- backward direction ----
    load_w(ws, 1, w, lane, onev, wh, wx, wp);
    run_dir<0>(lds, wh, wx, wp, bih_b, bhh_b, bb, w, lane, ln, par);
    __syncthreads();

    // ---- psi pass 2 (bwd half), both samples ----
    if (tid < Nn * NR) {
        const int i = tid / NR, c = tid - i * NR;
        const float* wu = lds + OFF_WU + c * 120 + 60;
        const float* s0 = lds + OFF_ST + i * 64;
        const float* s1 = lds + OFF_ST + 2048 + i * 64;
        float a0 = 0.f, a1 = 0.f;
#pragma unroll
        for (int k = 0; k < SP; ++k) {
            a0 = fmaf(wu[k], s0[k], a0);
            a1 = fmaf(wu[k], s1[k], a1);
        }
        lds[OFF_PSI + i * 8 + c] += a0;
        lds[OFF_PSI + 256 + i * 8 + c] += a1;
    }
    __syncthreads();

    if (w == 0) run_heads(lds, 0, b0, lane, out);
    else if (w == 1) run_heads(lds, 1, b0 + 1, lane, out);
}

}  // namespace

extern "C" void kernel_launch(void* const* d_in, const int* in_sizes, int n_in,
                              void* d_out, int out_size, void* d_ws, size_t ws_size,
                              hipStream_t stream) {
    (void)in_sizes; (void)n_in; (void)out_size; (void)ws_size;
    const float* has     = (const float*)d_in[0];
    const float* z       = (const float*)d_in[1];
    const float* dz      = (const float*)d_in[2];
    const unsigned* adjw = (const unsigned*)d_in[3];
    const float* Wih_f   = (const float*)d_in[4];
    const float* Whh_f   = (const float*)d_in[5];
    const float* bih_f   = (const float*)d_in[6];
    const float* bhh_f   = (const float*)d_in[7];
    const float* Wih_b   = (const float*)d_in[8];
    const float* Whh_b   = (const float*)d_in[9];
    const float* bih_b   = (const float*)d_in[10];
    const float* bhh_b   = (const float*)d_in[11];
    const float* Wf      = (const float*)d_in[12];
    const float* bf      = (const float*)d_in[13];
    const float* Wb      = (const float*)d_in[14];
    const float* bb      = (const float*)d_in[15];
    const float* Wa      = (const float*)d_in[16];
    const float* ba      = (const float*)d_in[17];
    const float* Wc      = (const float*)d_in[18];
    const float* bc      = (const float*)d_in[19];
    const float* Wu      = (const float*)d_in[20];
    const float* bu      = (const float*)d_in[21];
    float* out = (float*)d_out;
    float* ws  = (float*)d_ws;   // needs WS_TOTAL*4 = 237.6KB of scratch

    pack_kernel<<<(WS_TOTAL + 255) / 256, 256, 0, stream>>>(
        Whh_f, Wih_f, Wf, Whh_b, Wih_b, Wb, ws);

    dn_kernel<<<Bc / 2, 256, 0, stream>>>(
        has, z, dz, adjw,
        bih_f, bhh_f, bih_b, bhh_b, bf, bb,
        Wa, ba, Wc, bc, Wu, bu, ws, out);
}

// Round 12
// 340.402 us; speedup vs baseline: 1.3128x; 1.0155x over previous
//
#include <hip/hip_runtime.h>

// DesignerNetwork: B=1024 batch-independent graph-GRU network.
// Round 12: r11 structure (2 samples/block, packed d_ws, has-fold) with
// successor chunks widened 4 -> 6 (interval count -22%, finalize spread
// over all 4 waves as 12 tasks) and cold head weights (Wu/Wa/Wc/ba/bu/bc)
// evicted from LDS to global (psi/heads run once; L2 serves them). LDS
// 76.6KB -> still 2 blocks/CU. Launch bounds stay (256,2): min_waves>=4
// makes the allocator spill (r4/r9).

namespace {

typedef float v2f __attribute__((ext_vector_type(2)));

constexpr int Bc = 1024;   // batch
constexpr int Nn = 32;     // nodes
constexpr int SP = 60;     // S_PHI == S_RHO
constexpr int NA = 5;      // actions
constexpr int NR = 7;      // roles
constexpr int CHK = 6;     // successors per exchange round

// ---- d_ws float layout (packed weights) ----
// WHH: [dir2][gate3][lane64][wave4][16f]  = 24576 floats @ 0
// WIH: same                               = 24576 floats @ 24576
// WP : [dir2][lane64][wave4][20f]         = 10240 floats @ 49152
constexpr int WS_WIH = 24576;
constexpr int WS_WP  = 49152;
constexpr int WS_TOTAL = 59392;
constexpr int DSTRIDE_G = 12288;
constexpr int DSTRIDE_P = 5120;

// ---- LDS layout (float offsets) ----
constexpr int OFF_ST   = 0;        // states [2][32][64] = 4096
constexpr int OFF_RP   = 4096;     // rho partials [2par][2s][4w][64] = 1024
constexpr int OFF_PART = 5120;     // chunk partials [2s][6slot][4w][64][4] = 12288
constexpr int OFF_ZDZ  = 17408;    // z/dz [2][32][20] = 1280
constexpr int OFF_PSI  = 18688;    // psi raw [2][32][8] = 512
constexpr int OFF_HAS  = 19200;    // has [2][32]
constexpr int OFF_AF   = 19264;    // alpha_f [2][64]
constexpr int OFF_AB   = 19392;    // alpha_b [2][64]
constexpr int OFF_OS   = 19520;    // omega scratch [2][8]
constexpr int OFF_MASK = 19536;    // uints: succ[32] pred[32] flags[4]
constexpr int LDS_FLOATS = OFF_MASK + 68 + 8;   // 19612 floats = 76.6KB

__device__ __forceinline__ float sigm(float x) {
    return 1.0f / (1.0f + __expf(-x));
}

__device__ __forceinline__ float tanh_f(float x) {
    float e = __expf(fminf(2.0f * x, 80.0f));
    return (e - 1.0f) / (e + 1.0f);
}

// adj may arrive as int32 (0/1), packed uint8 bool, or float32. mode: 0/1/2.
__device__ __forceinline__ unsigned adj_nz(const unsigned* a, int mode, int r, int c) {
    const int idx = r * 32 + c;
    unsigned v = (mode == 1) ? ((a[idx >> 2] >> (8 * (idx & 3))) & 0xffu) : a[idx];
    return v != 0u ? 1u : 0u;
}

// 3-gate dot of weight slice with 8-v2f x slice (pads are zero both sides).
__device__ __forceinline__ void matvec3(const v2f (&W)[3][8], const v2f* x,
                                        float& r0, float& r1, float& r2) {
    v2f a0 = {0.f, 0.f}, a1 = {0.f, 0.f}, a2 = {0.f, 0.f};
#pragma unroll
    for (int p = 0; p < 8; ++p) {
        const v2f xp = x[p];
        a0 = __builtin_elementwise_fma(W[0][p], xp, a0);
        a1 = __builtin_elementwise_fma(W[1][p], xp, a1);
        a2 = __builtin_elementwise_fma(W[2][p], xp, a2);
    }
    r0 = a0.x + a0.y; r1 = a1.x + a1.y; r2 = a2.x + a2.y;
}

__device__ __forceinline__ void load_w(const float* __restrict__ ws, int d,
        int w, int lane, v2f onev,
        v2f (&wh)[3][8], v2f (&wx)[3][8], v2f (&wp)[10]) {
    const v2f* WH = (const v2f*)(ws + d * DSTRIDE_G + ((lane * 4 + w) << 4));
    const v2f* WX = (const v2f*)(ws + WS_WIH + d * DSTRIDE_G + ((lane * 4 + w) << 4));
    const v2f* WPp = (const v2f*)(ws + WS_WP + d * DSTRIDE_P + (lane * 4 + w) * 20);
#pragma unroll
    for (int g = 0; g < 3; ++g)
#pragma unroll
        for (int p = 0; p < 8; ++p) {
            wh[g][p] = WH[g * 2048 + p] * onev;
            wx[g][p] = WX[g * 2048 + p] * onev;
        }
#pragma unroll
    for (int p = 0; p < 10; ++p) wp[p] = WPp[p] * onev;
}

// ---- weight pre-pack kernel ----
__global__ void pack_kernel(const float* __restrict__ Whh_f, const float* __restrict__ Wih_f,
                            const float* __restrict__ Wf,
                            const float* __restrict__ Whh_b, const float* __restrict__ Wih_b,
                            const float* __restrict__ Wb, float* __restrict__ ws) {
    const int idx = blockIdx.x * 256 + threadIdx.x;
    if (idx < 2 * 24576) {
        const int which = idx / 24576;      // 0=WHH, 1=WIH
        int r = idx % 24576;
        const int j = r & 15; r >>= 4;
        const int w = r & 3;  r >>= 2;
        const int lane = r & 63; r >>= 6;
        const int g = r % 3;
        const int d = r / 3;
        const int k = 16 * w + j;
        const float* src = which ? (d ? Wih_b : Wih_f) : (d ? Whh_b : Whh_f);
        ws[idx] = (lane < 60 && k < 60) ? src[(g * 60 + lane) * 60 + k] : 0.f;
    } else if (idx < WS_TOTAL) {
        int r = idx - WS_WP;
        const int jj = r % 20; r /= 20;
        const int w = r & 3;  r >>= 2;
        const int lane = r & 63;
        const int d = r >> 6;
        const float* src = d ? Wb : Wf;
        const int pk = (w < 3) ? 20 * w : 60;
        ws[idx] = (lane < 60) ? src[lane * 80 + pk + jj] : 0.f;
    }
}

// GRU finalize from 4 partial float4s for one (sample, slot), has folded
// as multiplier: hnew = hold + m*(h2 - hold).
__device__ __forceinline__ void gru_fin(float* lds, int s, int slot, int lane,
        float b0s, float b1s, float b2i, float b2h,
        float* hrow, float m, bool act) {
    const int base = OFF_PART + ((s * CHK + slot) * 4) * 256;
    const float4 q0 = *(const float4*)(lds + base + (0 * 64 + lane) * 4);
    const float4 q1 = *(const float4*)(lds + base + (1 * 64 + lane) * 4);
    const float4 q2 = *(const float4*)(lds + base + (2 * 64 + lane) * 4);
    const float4 q3 = *(const float4*)(lds + base + (3 * 64 + lane) * 4);
    const float a0  = q0.x + q1.x + q2.x + q3.x + b0s;
    const float a1  = q0.y + q1.y + q2.y + q3.y + b1s;
    const float a2i = q0.z + q1.z + q2.z + q3.z + b2i;
    const float a2h = q0.w + q1.w + q2.w + q3.w + b2h;
    const float r = sigm(a0);
    const float u = sigm(a1);
    const float n = tanh_f(fmaf(r, a2h, a2i));
    const float hold = hrow[lane];
    const float h2 = fmaf(u, hold - n, n);
    const float hnew = fmaf(m, h2 - hold, hold);
    if (act) hrow[lane] = hnew;
}

template <int FWD>
__device__ __forceinline__ void run_dir(float* lds,
        const v2f (&wh)[3][8], const v2f (&wx)[3][8], const v2f (&wp)[10],
        const float* __restrict__ bih, const float* __restrict__ bhh,
        const float* __restrict__ bp, int w, int lane, int ln, int& par) {
    float* st0 = lds + OFF_ST;
    float* st1 = lds + OFF_ST + 2048;
    const unsigned* succm = (const unsigned*)(lds + OFF_MASK);
    const unsigned* predm = succm + 32;
    const bool act = lane < SP;

    const float b0s = bih[ln] + bhh[ln];
    const float b1s = bih[60 + ln] + bhh[60 + ln];
    const float b2i = bih[120 + ln];
    const float b2h = bhh[120 + ln];
    const float bpv = bp[ln];

    for (int s = 0; s < Nn; ++s) {
        const int t = FWD ? s : (Nn - 1 - s);

        // ---- finalize rho[t] for BOTH samples ----
        v2f pa0 = {0.f, 0.f}, pa1 = {0.f, 0.f};
        const v2f* xb0 = (w < 3) ? ((const v2f*)(st0 + t * 64) + 10 * w)
                                 : ((const v2f*)(lds + OFF_ZDZ + t * 20));
        const v2f* xb1 = (w < 3) ? ((const v2f*)(st1 + t * 64) + 10 * w)
                                 : ((const v2f*)(lds + OFF_ZDZ + 640 + t * 20));
#pragma unroll
        for (int p = 0; p < 10; ++p) {
            pa0 = __builtin_elementwise_fma(wp[p], xb0[p], pa0);
            pa1 = __builtin_elementwise_fma(wp[p], xb1[p], pa1);
        }
        lds[OFF_RP + ((par * 2 + 0) * 4 + w) * 64 + lane] = pa0.x + pa0.y;
        lds[OFF_RP + ((par * 2 + 1) * 4 + w) * 64 + lane] = pa1.x + pa1.y;
        __syncthreads();
        float sum0 = lds[OFF_RP + ((par * 2) * 4 + 0) * 64 + lane]
                   + lds[OFF_RP + ((par * 2) * 4 + 1) * 64 + lane]
                   + lds[OFF_RP + ((par * 2) * 4 + 2) * 64 + lane]
                   + lds[OFF_RP + ((par * 2) * 4 + 3) * 64 + lane] + bpv;
        float sum1 = lds[OFF_RP + ((par * 2 + 1) * 4 + 0) * 64 + lane]
                   + lds[OFF_RP + ((par * 2 + 1) * 4 + 1) * 64 + lane]
                   + lds[OFF_RP + ((par * 2 + 1) * 4 + 2) * 64 + lane]
                   + lds[OFF_RP + ((par * 2 + 1) * 4 + 3) * 64 + lane] + bpv;
        par ^= 1;
        const float rho0 = FWD ? tanh_f(sum0) : sum0;
        const float rho1 = FWD ? tanh_f(sum1) : sum1;
        if (act) { st0[t * 64 + lane] = rho0; st1[t * 64 + lane] = rho1; }
        // (own-wave LDS write->read below is in-order; no barrier needed)

        // ---- GRU pushes to successors, has folded as multiplier ----
        const float m0 = lds[OFF_HAS + t];
        const float m1 = lds[OFF_HAS + 32 + t];
        unsigned mk = (m0 != 0.f || m1 != 0.f) ? (FWD ? succm[t] : predm[t]) : 0u;
        if (mk) {
            float gA0, gA1, gA2, gB0, gB1, gB2;   // x-side per sample, per node
            matvec3(wx, (const v2f*)(st0 + t * 64) + 8 * w, gA0, gA1, gA2);
            matvec3(wx, (const v2f*)(st1 + t * 64) + 8 * w, gB0, gB1, gB2);
            while (mk) {
                int i0 = __ffs(mk) - 1; mk &= mk - 1u;
                int i1 = -1, i2 = -1, i3 = -1, i4 = -1, i5 = -1, cnt = 1;
                if (mk) { i1 = __ffs(mk) - 1; mk &= mk - 1u; ++cnt;
                 if (mk) { i2 = __ffs(mk) - 1; mk &= mk - 1u; ++cnt;
                  if (mk) { i3 = __ffs(mk) - 1; mk &= mk - 1u; ++cnt;
                   if (mk) { i4 = __ffs(mk) - 1; mk &= mk - 1u; ++cnt;
                    if (mk) { i5 = __ffs(mk) - 1; mk &= mk - 1u; ++cnt; } } } } }
                const int ii[CHK] = {i0, i1, i2, i3, i4, i5};
#pragma unroll
                for (int j = 0; j < CHK; ++j) {
                    if (j >= cnt) break;
                    float g0, g1, g2;
                    matvec3(wh, (const v2f*)(st0 + ii[j] * 64) + 8 * w, g0, g1, g2);
                    float4 q = {gA0 + g0, gA1 + g1, gA2, g2};
                    *(float4*)(lds + OFF_PART + (((0 * CHK + j) * 4 + w) * 64 + lane) * 4) = q;
                    matvec3(wh, (const v2f*)(st1 + ii[j] * 64) + 8 * w, g0, g1, g2);
                    float4 q2v = {gB0 + g0, gB1 + g1, gB2, g2};
                    *(float4*)(lds + OFF_PART + (((1 * CHK + j) * 4 + w) * 64 + lane) * 4) = q2v;
                }
                __syncthreads();
                {   // finalize: tasks = slot*2+sample, wave w takes w, w+4, w+8
                    const int nt = cnt * 2;
#pragma unroll
                    for (int rep = 0; rep < 3; ++rep) {
                        const int task = w + rep * 4;
                        if (task < nt) {
                            const int sl = task >> 1, sm = task & 1;
                            const int it = ii[sl];
                            float* hrow = (sm ? st1 : st0) + it * 64;
                            gru_fin(lds, sm, sl, lane, b0s, b1s, b2i, b2h,
                                    hrow, sm ? m1 : m0, act);
                        }
                    }
                }
                __syncthreads();
            }
        }
    }

    // ---- alpha scan (both samples; waves 0/1 finalize slot 0) ----
    float* ah0 = lds + (FWD ? OFF_AF : OFF_AB);
    float* ah1 = ah0 + 64;
    ah0[lane] = 0.f; ah1[lane] = 0.f;             // replicated identical write
    const int acn = FWD ? 5 : 6;
    for (int s2 = 0; s2 < acn; ++s2) {
        const int i = FWD ? (Nn - 5 + s2) : (5 - s2);
        const float m0 = lds[OFF_HAS + i];
        const float m1 = lds[OFF_HAS + 32 + i];
        if (m0 == 0.f && m1 == 0.f) continue;     // block-uniform skip
        float gA0, gA1, gA2, gB0, gB1, gB2, g0, g1, g2;
        matvec3(wx, (const v2f*)(st0 + i * 64) + 8 * w, gA0, gA1, gA2);
        matvec3(wh, (const v2f*)(ah0) + 8 * w, g0, g1, g2);
        float4 q = {gA0 + g0, gA1 + g1, gA2, g2};
        *(float4*)(lds + OFF_PART + (((0 * CHK) * 4 + w) * 64 + lane) * 4) = q;
        matvec3(wx, (const v2f*)(st1 + i * 64) + 8 * w, gB0, gB1, gB2);
        matvec3(wh, (const v2f*)(ah1) + 8 * w, g0, g1, g2);
        float4 q2v = {gB0 + g0, gB1 + g1, gB2, g2};
        *(float4*)(lds + OFF_PART + (((1 * CHK) * 4 + w) * 64 + lane) * 4) = q2v;
        __syncthreads();
        if (w == 0)      gru_fin(lds, 0, 0, lane, b0s, b1s, b2i, b2h, ah0, m0, act);
        else if (w == 1) gru_fin(lds, 1, 0, lane, b0s, b1s, b2i, b2h, ah1, m1, act);
        __syncthreads();
    }
}

__device__ void run_heads(float* lds, int s, int b, int lane,
                          const float* __restrict__ Wa, const float* __restrict__ ba,
                          const float* __restrict__ Wc, const float* __restrict__ bc,
                          const float* __restrict__ bu, float* __restrict__ out) {
    const float* aF = lds + OFF_AF + s * 64;
    const float* aB = lds + OFF_AB + s * 64;

    float o = 0.f;
    if (lane < NA) {
        o = ba[lane];
        const float* wa = Wa + lane * 120;
#pragma unroll
        for (int k = 0; k < SP; ++k) o = fmaf(wa[k], aF[k], o);
#pragma unroll
        for (int k = 0; k < SP; ++k) o = fmaf(wa[60 + k], aB[k], o);
        lds[OFF_OS + s * 8 + lane] = o;
    } else if (lane == NA) {
        float v = bc[0];
#pragma unroll
        for (int k = 0; k < SP; ++k) v = fmaf(Wc[k], aF[k], v);
#pragma unroll
        for (int k = 0; k < SP; ++k) v = fmaf(Wc[60 + k], aB[k], v);
        out[Bc * NA + Bc * NR * Nn + b] = v;
    }
    __builtin_amdgcn_wave_barrier();

    if (lane < NA) {
        const float* os = lds + OFF_OS + s * 8;
        float mx = os[0];
#pragma unroll
        for (int j = 1; j < NA; ++j) mx = fmaxf(mx, os[j]);
        float sum = 0.f;
#pragma unroll
        for (int j = 0; j < NA; ++j) sum += __expf(os[j] - mx);
        out[b * NA + lane] = __expf(o - mx) / sum;
    }

    if (lane < Nn) {
        const int i = lane;
        const float mkk = lds[OFF_HAS + s * 32 + i];
        float p[NR];
        float mx = -1e30f;
#pragma unroll
        for (int c = 0; c < NR; ++c) {
            const float v = (mkk != 0.f)
                ? (lds[OFF_PSI + s * 256 + i * 8 + c] + bu[c])
                : -60.0f;
            p[c] = v;
            mx = fmaxf(mx, v);
        }
        float sum = 0.f;
#pragma unroll
        for (int c = 0; c < NR; ++c) { p[c] = __expf(p[c] - mx); sum += p[c]; }
        const float inv = 1.0f / sum;
#pragma unroll
        for (int c = 0; c < NR; ++c)
            out[Bc * NA + b * (NR * Nn) + c * Nn + i] = p[c] * inv;
    }
}

__global__ __launch_bounds__(256, 2)
void dn_kernel(const float* __restrict__ has, const float* __restrict__ z,
               const float* __restrict__ dz, const unsigned* __restrict__ adjw,
               const float* __restrict__ bih_f, const float* __restrict__ bhh_f,
               const float* __restrict__ bih_b, const float* __restrict__ bhh_b,
               const float* __restrict__ bf, const float* __restrict__ bb,
               const float* __restrict__ Wa, const float* __restrict__ ba,
               const float* __restrict__ Wc, const float* __restrict__ bc,
               const float* __restrict__ Wu, const float* __restrict__ bu,
               const float* __restrict__ ws, float* __restrict__ out) {
    __shared__ float lds[LDS_FLOATS];
    const int tid = threadIdx.x;
    const int lane = tid & 63;
    const int w = tid >> 6;
    const int b0 = blockIdx.x * 2;
    const int ln = (lane < SP) ? lane : (SP - 1);   // clamp for bias loads

    unsigned* succm = (unsigned*)(lds + OFF_MASK);
    unsigned* predm = succm + 32;
    unsigned* flags = predm + 32;

    if (tid < 4) flags[tid] = 0u;
    __syncthreads();

    // ---- adj dtype detection (first 256 words only) ----
    {
        unsigned ff = 0u, fb = 0u;
        for (int i = tid; i < 256; i += 256) {
            const unsigned v = adjw[i];
            ff |= (v == 0x3f800000u) ? 1u : 0u;
            fb |= (v > 1u && v != 0x3f800000u) ? 1u : 0u;
        }
        if (ff) atomicOr(&flags[0], 1u);
        if (fb) atomicOr(&flags[1], 1u);
    }

    // ---- stage has, z/dz (both samples); zero states ----
    if (tid < 64) lds[OFF_HAS + tid] = has[(b0 + (tid >> 5)) * 32 + (tid & 31)];
    for (int i = tid; i < 2 * Nn * 20; i += 256) {
        const int ss = i / 640, r = i - ss * 640;
        const int t = r / 20, k = r - t * 20;
        lds[OFF_ZDZ + i] = (k < 10) ? z[((b0 + ss) * Nn + t) * 10 + k]
                                    : dz[((b0 + ss) * Nn + t) * 10 + (k - 10)];
    }
    for (int i = tid; i < 2 * Nn * 64; i += 256) lds[OFF_ST + i] = 0.f;
    __syncthreads();

    // ---- adjacency bitmasks ----
    const int mode = flags[0] ? 2 : (flags[1] ? 1 : 0);
    if (tid < 32) {
        unsigned sm = 0u;
        for (int c = 0; c < 32; ++c) sm |= adj_nz(adjw, mode, tid, c) << c;
        succm[tid] = sm;
    } else if (tid < 64) {
        const int c = tid - 32;
        unsigned pm = 0u;
        for (int r = 0; r < 32; ++r) pm |= adj_nz(adjw, mode, r, c) << r;
        predm[c] = pm;
    }
    __syncthreads();

    // ---- opaque 1.0f (discourages rematerialization of weight loads) ----
    float one = 1.0f;
    asm volatile("" : "+v"(one));
    const v2f onev = {one, one};

    int par = 0;
    v2f wh[3][8], wx[3][8], wp[10];

    // ---- forward direction ----
    load_w(ws, 0, w, lane, onev, wh, wx, wp);
    run_dir<1>(lds, wh, wx, wp, bih_f, bhh_f, bf, w, lane, ln, par);
    __syncthreads();

    // ---- psi pass 1 (fwd half), both samples; Wu from global ----
    if (tid < Nn * NR) {
        const int i = tid / NR, c = tid - i * NR;
        const float* wu = Wu + c * 120;
        const float* s0 = lds + OFF_ST + i * 64;
        const float* s1 = lds + OFF_ST + 2048 + i * 64;
        float a0 = 0.f, a1 = 0.f;
#pragma unroll
        for (int k = 0; k < SP; ++k) {
            a0 = fmaf(wu[k], s0[k], a0);
            a1 = fmaf(wu[k], s1[k], a1);
        }
        lds[OFF_PSI + i * 8 + c] = a0;
        lds[OFF_PSI + 256 + i * 8 + c] = a1;
    }
    __syncthreads();

    // ---- re-zero states for backward direction ----
    for (int i = tid; i < 2 * Nn * 64; i += 256) lds[OFF_ST + i] = 0.f;
    __syncthreads();

    // ---- backward direction ----
    load_w(ws, 1, w, lane, onev, wh, wx, wp);
    run_dir<0>(lds, wh, wx, wp, bih_b, bhh_b, bb, w, lane, ln, par);
    __syncthreads();

    // ---- psi pass 2 (bwd half), both samples ----
    if (tid < Nn * NR) {
        const int i = tid / NR, c = tid - i * NR;
        const float* wu = Wu + c * 120 + 60;
        const float* s0 = lds + OFF_ST + i * 64;
        const float* s1 = lds + OFF_ST + 2048 + i * 64;
        float a0 = 0.f, a1 = 0.f;
#pragma unroll
        for (int k = 0; k < SP; ++k) {
            a0 = fmaf(wu[k], s0[k], a0);
            a1 = fmaf(wu[k], s1[k], a1);
        }
        lds[OFF_PSI + i * 8 + c] += a0;
        lds[OFF_PSI + 256 + i * 8 + c] += a1;
    }
    __syncthreads();

    if (w == 0) run_heads(lds, 0, b0, lane, Wa, ba, Wc, bc, bu, out);
    else if (w == 1) run_heads(lds, 1, b0 + 1, lane, Wa, ba, Wc, bc, bu, out);
}

}  // namespace

extern "C" void kernel_launch(void* const* d_in, const int* in_sizes, int n_in,
                              void* d_out, int out_size, void* d_ws, size_t ws_size,
                              hipStream_t stream) {
    (void)in_sizes; (void)n_in; (void)out_size; (void)ws_size;
    const float* has     = (const float*)d_in[0];
    const float* z       = (const float*)d_in[1];
    const float* dz      = (const float*)d_in[2];
    const unsigned* adjw = (const unsigned*)d_in[3];
    const float* Wih_f   = (const float*)d_in[4];
    const float* Whh_f   = (const float*)d_in[5];
    const float* bih_f   = (const float*)d_in[6];
    const float* bhh_f   = (const float*)d_in[7];
    const float* Wih_b   = (const float*)d_in[8];
    const float* Whh_b   = (const float*)d_in[9];
    const float* bih_b   = (const float*)d_in[10];
    const float* bhh_b   = (const float*)d_in[11];
    const float* Wf      = (const float*)d_in[12];
    const float* bf      = (const float*)d_in[13];
    const float* Wb      = (const float*)d_in[14];
    const float* bb      = (const float*)d_in[15];
    const float* Wa      = (const float*)d_in[16];
    const float* ba      = (const float*)d_in[17];
    const float* Wc      = (const float*)d_in[18];
    const float* bc      = (const float*)d_in[19];
    const float* Wu      = (const float*)d_in[20];
    const float* bu      = (const float*)d_in[21];
    float* out = (float*)d_out;
    float* ws  = (float*)d_ws;   // needs WS_TOTAL*4 = 237.6KB of scratch

    pack_kernel<<<(WS_TOTAL + 255) / 256, 256, 0, stream>>>(
        Whh_f, Wih_f, Wf, Whh_b, Wih_b, Wb, ws);

    dn_kernel<<<Bc / 2, 256, 0, stream>>>(
        has, z, dz, adjw,
        bih_f, bhh_f, bih_b, bhh_b, bf, bb,
        Wa, ba, Wc, bc, Wu, bu, ws, out);
}